// Round 15
// baseline (110.893 us; speedup 1.0000x reference)
//
#include <hip/hip_runtime.h>

namespace {

constexpr int T   = 30;
constexpr int C   = 4;
constexpr int HW  = 256 * 256;
constexpr int B   = 8;
constexpr int CHW = C * HW;
constexpr int BLK = 1024;                    // 16 waves/block

typedef _Float16 f16x2 __attribute__((ext_vector_type(2)));

// R13 structure exactly (cached loads, nt stores, channel-PAIR load
// batches + sched_barrier(0), f16x2 scan arrays, (4,4) spill-free pin).
// Single change: block 256 -> 1024 threads. A block's 16 waves issue
// their 30-plane load batches in the same window, so each t-plane sees
// 4 KB of contiguous same-DRAM-row requests from one CU (vs 1 KB),
// quadrupling effective burst length. Codegen/occupancy unchanged.
__global__ __attribute__((amdgpu_flat_work_group_size(BLK, BLK)))
           __attribute__((amdgpu_waves_per_eu(4, 4)))
void interp_kernel(
    const float* __restrict__ images,
    const float* __restrict__ mask,
    const float* __restrict__ days,
    float* __restrict__ out)
{
    __shared__ float s_day[T];
    const int tid = threadIdx.x;
    const int b   = blockIdx.x >> 6;            // 64 blocks per batch image
    if (tid < T) s_day[tid] = days[b * T + tid];
    __syncthreads();

    const int hw = ((blockIdx.x & 63) << 10) | tid;

    // ---- visibility bitmask: 30 batched cached loads ----
    const float* mbase = mask + (size_t)b * T * HW + hw;
    unsigned vis = 0u;
    {
        float mv[T];
#pragma unroll
        for (int t = 0; t < T; ++t) mv[t] = mbase[(size_t)t * HW];
        __builtin_amdgcn_sched_barrier(0);
#pragma unroll
        for (int t = 0; t < T; ++t) vis |= (mv[t] == 0.0f ? 1u : 0u) << t;
    }

    // ---- fr[]: backward day-of-next-visible scan (f16 exact: integer
    //      days), then transformed in place to frac on the forward pass ----
    f16x2 fr[T / 2];
    {
        float run = 0.0f;
#pragma unroll
        for (int t = T - 1; t >= 0; --t) {
            run = ((vis >> t) & 1u) ? s_day[t] : run;
            if (t & 1) fr[t >> 1].y = (_Float16)run;
            else       fr[t >> 1].x = (_Float16)run;
        }
        float dl = 0.0f;
#pragma unroll
        for (int t = 0; t < T; ++t) {
            const float d = s_day[t];
            dl = ((vis >> t) & 1u) ? d : dl;
            const float dn = (t & 1) ? (float)fr[t >> 1].y
                                     : (float)fr[t >> 1].x;
            float den = dn - dl;
            den = (den == 0.0f) ? 1.0f : den;
            float f = (d - dl) / den;
            const bool lv_ok = (vis & ((1u << (t + 1)) - 1u)) != 0u;
            const bool nv_ok = (vis >> t) != 0u;
            // visible/only_last/none -> 0 ; only_next -> 1 (rl==0 => img_next)
            f = (lv_ok && nv_ok) ? f : (nv_ok ? 1.0f : 0.0f);
            if (t & 1) fr[t >> 1].y = (_Float16)f;
            else       fr[t >> 1].x = (_Float16)f;
        }
    }

    const bool  none = (vis == 0u);
    const float nanv = __int_as_float(0x7fc00000);
    const size_t pixBase = (size_t)b * T * CHW + hw;

#pragma unroll 1
    for (int cp = 0; cp < C / 2; ++cp) {
        const int c0 = cp * 2;
        const float* ib0 = images + pixBase + (size_t)c0 * HW;
        const float* ib1 = ib0 + HW;
        float*       ob0 = out    + pixBase + (size_t)c0 * HW;
        float*       ob1 = ob0 + HW;

        // 60 batched cached loads (two channels) into explicit live arrays
        float v0[T], v1[T];
#pragma unroll
        for (int t = 0; t < T; ++t) v0[t] = ib0[(size_t)t * CHW];
#pragma unroll
        for (int t = 0; t < T; ++t) v1[t] = ib1[(size_t)t * CHW];
        __builtin_amdgcn_sched_barrier(0);

        // ---- channel 0: scan + store (ch1 loads still in flight) ----
        {
            f16x2 nvp[T / 2];
            float run = 0.0f;
#pragma unroll
            for (int t = T - 1; t >= 0; --t) {
                run = ((vis >> t) & 1u) ? v0[t] : run;
                if (t & 1) nvp[t >> 1].y = (_Float16)run;
                else       nvp[t >> 1].x = (_Float16)run;
            }
            float rl = 0.0f;
#pragma unroll
            for (int t = 0; t < T; ++t) {
                const float nv = (t & 1) ? (float)nvp[t >> 1].y
                                         : (float)nvp[t >> 1].x;
                rl = ((vis >> t) & 1u) ? nv : rl;
                const float f  = (t & 1) ? (float)fr[t >> 1].y
                                         : (float)fr[t >> 1].x;
                const float res = fmaf(f, nv - rl, rl);
                __builtin_nontemporal_store(none ? nanv : res,
                                            &ob0[(size_t)t * CHW]);
            }
        }
        // ---- channel 1: scan + store ----
        {
            f16x2 nvp[T / 2];
            float run = 0.0f;
#pragma unroll
            for (int t = T - 1; t >= 0; --t) {
                run = ((vis >> t) & 1u) ? v1[t] : run;
                if (t & 1) nvp[t >> 1].y = (_Float16)run;
                else       nvp[t >> 1].x = (_Float16)run;
            }
            float rl = 0.0f;
#pragma unroll
            for (int t = 0; t < T; ++t) {
                const float nv = (t & 1) ? (float)nvp[t >> 1].y
                                         : (float)nvp[t >> 1].x;
                rl = ((vis >> t) & 1u) ? nv : rl;
                const float f  = (t & 1) ? (float)fr[t >> 1].y
                                         : (float)fr[t >> 1].x;
                const float res = fmaf(f, nv - rl, rl);
                __builtin_nontemporal_store(none ? nanv : res,
                                            &ob1[(size_t)t * CHW]);
            }
        }
    }
}

} // namespace

extern "C" void kernel_launch(void* const* d_in, const int* in_sizes, int n_in,
                              void* d_out, int out_size, void* d_ws, size_t ws_size,
                              hipStream_t stream)
{
    const float* images = (const float*)d_in[0];
    const float* mask   = (const float*)d_in[1];
    const float* days   = (const float*)d_in[2];
    float* out          = (float*)d_out;

    const int nPix = B * HW;                 // one thread per (b, h, w)
    dim3 grid(nPix / BLK), block(BLK);
    hipLaunchKernelGGL(interp_kernel, grid, block, 0, stream,
                       images, mask, days, out);
}

// Round 16
// 105.402 us; speedup vs baseline: 1.0521x; 1.0521x over previous
//
#include <hip/hip_runtime.h>

namespace {

constexpr int T   = 30;
constexpr int C   = 4;
constexpr int HW  = 256 * 256;
constexpr int B   = 8;
constexpr int CHW = C * HW;

typedef _Float16 f16x2 __attribute__((ext_vector_type(2)));

// FINAL (revert to R13, the measured best at 103.4 us):
// - one thread per (b,h,w) pixel; fully predicated register scans
//   (cummax/cummin carried as values, zero divergence)
// - cached LOADS: inputs stay L3-resident across graph replays
//   (FETCH 313 -> 154 MB); nt STORES so the 252 MB output stream
//   doesn't evict them (WRITE = 246 MB = exact ideal)
// - explicit v[30] load batches + sched_barrier(0): backend keeps all
//   30 loads in flight (without this the scheduler sinks them; R9
//   collapsed to latency-bound 198 us)
// - channel-PAIR batching: 60 loads in flight, ch0's scan+store
//   overlaps ch1's loads -> 1 interior stall window instead of 3
// - f16x2-packed scan arrays (days are integer-valued -> f16 exact;
//   value rounding adds <=~3e-3 vs 0.108 threshold)
// - waves_per_eu(4,4): the only allocator operating point proven
//   spill-free at VGPR=52 (tested 3/5/6/8: all squeeze or regress)
// Lever sweep exhausted (occupancy/width/block-size/pipeline-depth/
// cache-mode); 5.4 TB/s demand on a 30-plane-interleaved 256B-granule
// stream == this pattern's practical ceiling (linear copy = 6.3).
__global__ __attribute__((amdgpu_flat_work_group_size(256, 256)))
           __attribute__((amdgpu_waves_per_eu(4, 4)))
void interp_kernel(
    const float* __restrict__ images,
    const float* __restrict__ mask,
    const float* __restrict__ days,
    float* __restrict__ out)
{
    __shared__ float s_day[T];
    const int tid = threadIdx.x;
    const int b   = blockIdx.x >> 8;            // 256 blocks per batch image
    if (tid < T) s_day[tid] = days[b * T + tid];
    __syncthreads();

    const int hw = ((blockIdx.x & 255) << 8) | tid;

    // ---- visibility bitmask: 30 batched cached loads ----
    const float* mbase = mask + (size_t)b * T * HW + hw;
    unsigned vis = 0u;
    {
        float mv[T];
#pragma unroll
        for (int t = 0; t < T; ++t) mv[t] = mbase[(size_t)t * HW];
        __builtin_amdgcn_sched_barrier(0);
#pragma unroll
        for (int t = 0; t < T; ++t) vis |= (mv[t] == 0.0f ? 1u : 0u) << t;
    }

    // ---- fr[]: backward day-of-next-visible scan (f16 exact: integer
    //      days), then transformed in place to frac on the forward pass ----
    f16x2 fr[T / 2];
    {
        float run = 0.0f;
#pragma unroll
        for (int t = T - 1; t >= 0; --t) {
            run = ((vis >> t) & 1u) ? s_day[t] : run;
            if (t & 1) fr[t >> 1].y = (_Float16)run;
            else       fr[t >> 1].x = (_Float16)run;
        }
        float dl = 0.0f;
#pragma unroll
        for (int t = 0; t < T; ++t) {
            const float d = s_day[t];
            dl = ((vis >> t) & 1u) ? d : dl;
            const float dn = (t & 1) ? (float)fr[t >> 1].y
                                     : (float)fr[t >> 1].x;
            float den = dn - dl;
            den = (den == 0.0f) ? 1.0f : den;
            float f = (d - dl) / den;
            const bool lv_ok = (vis & ((1u << (t + 1)) - 1u)) != 0u;
            const bool nv_ok = (vis >> t) != 0u;
            // visible/only_last/none -> 0 ; only_next -> 1 (rl==0 => img_next)
            f = (lv_ok && nv_ok) ? f : (nv_ok ? 1.0f : 0.0f);
            if (t & 1) fr[t >> 1].y = (_Float16)f;
            else       fr[t >> 1].x = (_Float16)f;
        }
    }

    const bool  none = (vis == 0u);
    const float nanv = __int_as_float(0x7fc00000);
    const size_t pixBase = (size_t)b * T * CHW + hw;

#pragma unroll 1
    for (int cp = 0; cp < C / 2; ++cp) {
        const int c0 = cp * 2;
        const float* ib0 = images + pixBase + (size_t)c0 * HW;
        const float* ib1 = ib0 + HW;
        float*       ob0 = out    + pixBase + (size_t)c0 * HW;
        float*       ob1 = ob0 + HW;

        // 60 batched cached loads (two channels) into explicit live arrays
        float v0[T], v1[T];
#pragma unroll
        for (int t = 0; t < T; ++t) v0[t] = ib0[(size_t)t * CHW];
#pragma unroll
        for (int t = 0; t < T; ++t) v1[t] = ib1[(size_t)t * CHW];
        __builtin_amdgcn_sched_barrier(0);

        // ---- channel 0: scan + store (ch1 loads still in flight) ----
        {
            f16x2 nvp[T / 2];
            float run = 0.0f;
#pragma unroll
            for (int t = T - 1; t >= 0; --t) {
                run = ((vis >> t) & 1u) ? v0[t] : run;
                if (t & 1) nvp[t >> 1].y = (_Float16)run;
                else       nvp[t >> 1].x = (_Float16)run;
            }
            float rl = 0.0f;
#pragma unroll
            for (int t = 0; t < T; ++t) {
                const float nv = (t & 1) ? (float)nvp[t >> 1].y
                                         : (float)nvp[t >> 1].x;
                rl = ((vis >> t) & 1u) ? nv : rl;
                const float f  = (t & 1) ? (float)fr[t >> 1].y
                                         : (float)fr[t >> 1].x;
                const float res = fmaf(f, nv - rl, rl);
                __builtin_nontemporal_store(none ? nanv : res,
                                            &ob0[(size_t)t * CHW]);
            }
        }
        // ---- channel 1: scan + store ----
        {
            f16x2 nvp[T / 2];
            float run = 0.0f;
#pragma unroll
            for (int t = T - 1; t >= 0; --t) {
                run = ((vis >> t) & 1u) ? v1[t] : run;
                if (t & 1) nvp[t >> 1].y = (_Float16)run;
                else       nvp[t >> 1].x = (_Float16)run;
            }
            float rl = 0.0f;
#pragma unroll
            for (int t = 0; t < T; ++t) {
                const float nv = (t & 1) ? (float)nvp[t >> 1].y
                                         : (float)nvp[t >> 1].x;
                rl = ((vis >> t) & 1u) ? nv : rl;
                const float f  = (t & 1) ? (float)fr[t >> 1].y
                                         : (float)fr[t >> 1].x;
                const float res = fmaf(f, nv - rl, rl);
                __builtin_nontemporal_store(none ? nanv : res,
                                            &ob1[(size_t)t * CHW]);
            }
        }
    }
}

} // namespace

extern "C" void kernel_launch(void* const* d_in, const int* in_sizes, int n_in,
                              void* d_out, int out_size, void* d_ws, size_t ws_size,
                              hipStream_t stream)
{
    const float* images = (const float*)d_in[0];
    const float* mask   = (const float*)d_in[1];
    const float* days   = (const float*)d_in[2];
    float* out          = (float*)d_out;

    const int nPix = B * HW;                 // one thread per (b, h, w)
    dim3 grid(nPix / 256), block(256);
    hipLaunchKernelGGL(interp_kernel, grid, block, 0, stream,
                       images, mask, days, out);
}